// Round 12
// baseline (198.458 us; speedup 1.0000x reference)
//
#include <hip/hip_runtime.h>

#define D_DIRS 1296
#define K_PTS  64
#define R_RANK 16
#define F_SUB  408
#define DT_VAL (200.0f / 64.0f)

#define NBLOCKS (D_DIRS / 2)                 // 648 blocks, 2 dirs sequential
#define PARTIAL_FLOATS 8704                  // 8192 T + 512 G per slab
#define RED_CHUNKS 12
#define SLABS_PER_CHUNK (NBLOCKS / RED_CHUNKS)   // 54
#define NEED_BYTES ((size_t)(1 + RED_CHUNKS + NBLOCKS) * PARTIAL_FLOATS * 4)

// Packed fp32 FMA: acc.x += m.x*s.x ; acc.y += m.y*s.y  (one VALU inst).
// "+v" pins the accumulator in arch VGPRs (defeats AGPR parking, the 3x
// VALU inflation seen in r8-r11); "s" sources the wave-uniform att row
// from SGPRs (s_load), costing zero LDS/VGPR bandwidth.
#define PK(acc, m, s) \
    asm("v_pk_fma_f32 %0, %1, %2, %0" : "+v"(acc) : "v"(m), "s"(s))

// ---------------------------------------------------------------------------
// accum: 2 dirs sequential per block; thread t owns (i=t>>4, j=t&15).
// Reverse-cumsum: S(k) = sum_{k'>=max(k,1)} conj(rad_i)conj(att_j)
//   T[i,j,l] = dt * sum_k att_l(k) * S(max(k,1));  G[i,j] = S(1) + w(0)
// Per k: per-lane reads rad_i, att_j from LDS (2x ds_read_b64); the
// broadcast att row comes from GLOBAL via uniform s_load (planar layout is
// already pk-pair-ready); 32 v_pk_fma_f32 do the 16 complex accumulates.
// ---------------------------------------------------------------------------
template <bool USE_PARTIALS>
__global__ __launch_bounds__(256) void accum_kernel_t(
    const float* __restrict__ att_r, const float* __restrict__ att_i,
    const float* __restrict__ rad_r, const float* __restrict__ rad_i,
    float* __restrict__ pbuf, float* __restrict__ atomic_dst)
{
    __shared__ float2 sAtt[2][K_PTS * R_RANK];   // [h][k*16+idx] = {re,im}
    __shared__ float2 sRad[2][K_PTS * R_RANK];

    const int t = threadIdx.x;
    const int i = t >> 4;
    const int j = t & 15;

    for (int h = 0; h < 2; ++h) {
        const int base = (blockIdx.x * 2 + h) * (K_PTS * R_RANK);
#pragma unroll
        for (int s = t; s < 512; s += 256) {
            float2 ar = *(const float2*)(att_r + base + 2 * s);
            float2 ai = *(const float2*)(att_i + base + 2 * s);
            sAtt[h][2 * s]     = make_float2(ar.x, ai.x);
            sAtt[h][2 * s + 1] = make_float2(ar.y, ai.y);
            float2 rr = *(const float2*)(rad_r + base + 2 * s);
            float2 rm = *(const float2*)(rad_i + base + 2 * s);
            sRad[h][2 * s]     = make_float2(rr.x, rm.x);
            sRad[h][2 * s + 1] = make_float2(rr.y, rm.y);
        }
    }
    __syncthreads();

    float2 accR[8], accI[8];   // accR[q] = {T_r[2q], T_r[2q+1]}, etc.
#pragma unroll
    for (int q = 0; q < 8; ++q) {
        accR[q] = make_float2(0.f, 0.f);
        accI[q] = make_float2(0.f, 0.f);
    }
    float gR = 0.f, gI = 0.f;

    for (int h = 0; h < 2; ++h) {
        const float2* A2 = sAtt[h];
        const float2* R2 = sRad[h];
        const float*  gre = att_r + (blockIdx.x * 2 + h) * (K_PTS * R_RANK);
        const float*  gim = att_i + (blockIdx.x * 2 + h) * (K_PTS * R_RANK);

        float Sr = 0.f, Si = 0.f;
        for (int k = K_PTS - 1; k >= 1; --k) {
            float2 a = R2[k * 16 + i];
            float2 b = A2[k * 16 + j];
            Sr += a.x * b.x - a.y * b.y;      // S += conj(rad)_i*conj(att)_j
            Si -= a.x * b.y + a.y * b.x;
            float2 SrP = make_float2(Sr, Sr);
            float2 SiP = make_float2(Si, Si);
            float2 SiN = make_float2(-Si, -Si);
            const float4* re4 = (const float4*)(gre + k * 16);  // uniform -> s_load
            const float4* im4 = (const float4*)(gim + k * 16);
#pragma unroll
            for (int q = 0; q < 4; ++q) {
                float4 re = re4[q], im = im4[q];
                float2 reL = make_float2(re.x, re.y), reH = make_float2(re.z, re.w);
                float2 imL = make_float2(im.x, im.y), imH = make_float2(im.z, im.w);
                PK(accR[2 * q],     SrP, reL);  PK(accR[2 * q],     SiN, imL);
                PK(accR[2 * q + 1], SrP, reH);  PK(accR[2 * q + 1], SiN, imH);
                PK(accI[2 * q],     SrP, imL);  PK(accI[2 * q],     SiP, reL);
                PK(accI[2 * q + 1], SrP, imH);  PK(accI[2 * q + 1], SiP, reH);
            }
        }
        // k = 0: T-term uses S(1) (current S); G = S(1) + w(0)
        {
            float2 SrP = make_float2(Sr, Sr);
            float2 SiP = make_float2(Si, Si);
            float2 SiN = make_float2(-Si, -Si);
            const float4* re4 = (const float4*)gre;
            const float4* im4 = (const float4*)gim;
#pragma unroll
            for (int q = 0; q < 4; ++q) {
                float4 re = re4[q], im = im4[q];
                float2 reL = make_float2(re.x, re.y), reH = make_float2(re.z, re.w);
                float2 imL = make_float2(im.x, im.y), imH = make_float2(im.z, im.w);
                PK(accR[2 * q],     SrP, reL);  PK(accR[2 * q],     SiN, imL);
                PK(accR[2 * q + 1], SrP, reH);  PK(accR[2 * q + 1], SiN, imH);
                PK(accI[2 * q],     SrP, imL);  PK(accI[2 * q],     SiP, reL);
                PK(accI[2 * q + 1], SrP, imH);  PK(accI[2 * q + 1], SiP, reH);
            }
            float2 a0 = R2[i], b0 = A2[j];
            gR += Sr + (a0.x * b0.x - a0.y * b0.y);
            gI += Si - (a0.x * b0.y + a0.y * b0.x);
        }
    }

    // ---- emit (dt applied to T here; layout e = ((i*16+j)*16 + l)*2 + c)
    if (USE_PARTIALS) {
        float4* slabT = (float4*)(pbuf + (size_t)blockIdx.x * PARTIAL_FLOATS);
#pragma unroll
        for (int q = 0; q < 8; ++q) {
            slabT[t * 8 + q] = make_float4(
                accR[q].x * DT_VAL, accI[q].x * DT_VAL,
                accR[q].y * DT_VAL, accI[q].y * DT_VAL);
        }
        float2* slabG = (float2*)(pbuf + (size_t)blockIdx.x * PARTIAL_FLOATS + 8192);
        slabG[t] = make_float2(gR, gI);
    } else {
#pragma unroll
        for (int q = 0; q < 8; ++q) {
            atomicAdd(&atomic_dst[(t * 16 + 2 * q) * 2 + 0], accR[q].x * DT_VAL);
            atomicAdd(&atomic_dst[(t * 16 + 2 * q) * 2 + 1], accI[q].x * DT_VAL);
            atomicAdd(&atomic_dst[(t * 16 + 2 * q + 1) * 2 + 0], accR[q].y * DT_VAL);
            atomicAdd(&atomic_dst[(t * 16 + 2 * q + 1) * 2 + 1], accI[q].y * DT_VAL);
        }
        atomicAdd(&atomic_dst[8192 + t * 2 + 0], gR);
        atomicAdd(&atomic_dst[8192 + t * 2 + 1], gI);
    }
}

// ---------------------------------------------------------------------------
// reduce1: chunk c (blockIdx.y) sums its 54 slabs elementwise into red1[c].
// reduce2: sums the 12 chunks into the final 34 KB TG buffer (r11 lesson:
// folding this into contract made 408 blocks re-read 170 MB).
// ---------------------------------------------------------------------------
__global__ __launch_bounds__(256) void reduce1_kernel(
    const float* __restrict__ pbuf, float* __restrict__ red1)
{
    int e = blockIdx.x * 256 + threadIdx.x;              // 34*256 == 8704
    const float* p = pbuf + (size_t)blockIdx.y * SLABS_PER_CHUNK * PARTIAL_FLOATS + e;
    float s = 0.f;
#pragma unroll 6
    for (int b = 0; b < SLABS_PER_CHUNK; ++b)
        s += p[(size_t)b * PARTIAL_FLOATS];
    red1[blockIdx.y * PARTIAL_FLOATS + e] = s;
}

__global__ __launch_bounds__(256) void reduce2_kernel(
    const float* __restrict__ red1, float* __restrict__ TG_out)
{
    int e = blockIdx.x * 256 + threadIdx.x;
    float s = 0.f;
#pragma unroll
    for (int c = 0; c < RED_CHUNKS; ++c)
        s += red1[c * PARTIAL_FLOATS + e];
    TG_out[e] = s;
}

// ---------------------------------------------------------------------------
// contract:  csi[f] = (dt/D) * sum_{ij}(G + sum_l T f_l) f_i f_j
// One block per f; T/G read from the final 34 KB buffer (L2-resident).
// OUTPUT: float32 PLANAR — out[f] = re, out[F_SUB+f] = im.
// ---------------------------------------------------------------------------
__global__ __launch_bounds__(256) void contract_kernel(
    const float* __restrict__ fr, const float* __restrict__ fi,
    const float* __restrict__ T_ws, const float* __restrict__ G_ws,
    float* __restrict__ out)
{
    const int f = blockIdx.x;
    const int t = threadIdx.x;
    const int i = t >> 4;
    const int j = t & 15;

    __shared__ float sfr[16], sfi[16];
    if (t < 16) {
        sfr[t] = fr[f * R_RANK + t];
        sfi[t] = fi[f * R_RANK + t];
    }
    __syncthreads();

    float fir = sfr[i], fii = sfi[i];
    float fjr = sfr[j], fji = sfi[j];
    float mr = fir * fjr - fii * fji;   // f_i * f_j
    float mi = fir * fji + fii * fjr;

    float Sr = G_ws[t * 2 + 0];
    float Si = G_ws[t * 2 + 1];
#pragma unroll
    for (int l = 0; l < 16; ++l) {
        float Tr = T_ws[(t * 16 + l) * 2 + 0];
        float Ti = T_ws[(t * 16 + l) * 2 + 1];
        float flr = sfr[l], fli = sfi[l];
        Sr += Tr * flr - Ti * fli;
        Si += Tr * fli + Ti * flr;
    }

    float vr = Sr * mr - Si * mi;
    float vi = Sr * mi + Si * mr;

#pragma unroll
    for (int off = 32; off >= 1; off >>= 1) {
        vr += __shfl_down(vr, off, 64);
        vi += __shfl_down(vi, off, 64);
    }
    __shared__ float red[8];
    const int lane = t & 63, w = t >> 6;
    if (lane == 0) { red[w * 2] = vr; red[w * 2 + 1] = vi; }
    __syncthreads();
    if (t == 0) {
        float rr = red[0] + red[2] + red[4] + red[6];
        float ii = red[1] + red[3] + red[5] + red[7];
        const float scale = DT_VAL / (float)D_DIRS;
        out[f]         = rr * scale;
        out[F_SUB + f] = ii * scale;
    }
}

// ---------------------------------------------------------------------------
extern "C" void kernel_launch(void* const* d_in, const int* in_sizes, int n_in,
                              void* d_out, int out_size, void* d_ws, size_t ws_size,
                              hipStream_t stream)
{
    const float* att_r = (const float*)d_in[0];
    const float* att_i = (const float*)d_in[1];
    const float* rad_r = (const float*)d_in[2];
    const float* rad_i = (const float*)d_in[3];
    const float* fr    = (const float*)d_in[4];
    const float* fi    = (const float*)d_in[5];

    float* ws   = (float*)d_ws;
    float* TG   = ws;                                    // 8704 floats (T then G)
    float* red1 = ws + PARTIAL_FLOATS;                   // 12 * 8704
    float* pbuf = ws + (1 + RED_CHUNKS) * PARTIAL_FLOATS;

    const bool use_partials = ws_size >= NEED_BYTES;

    if (use_partials) {
        accum_kernel_t<true><<<NBLOCKS, 256, 0, stream>>>(
            att_r, att_i, rad_r, rad_i, pbuf, TG);
        reduce1_kernel<<<dim3(PARTIAL_FLOATS / 256, RED_CHUNKS), 256, 0, stream>>>(
            pbuf, red1);
        reduce2_kernel<<<PARTIAL_FLOATS / 256, 256, 0, stream>>>(red1, TG);
    } else {
        hipMemsetAsync(TG, 0, PARTIAL_FLOATS * sizeof(float), stream);
        accum_kernel_t<false><<<NBLOCKS, 256, 0, stream>>>(
            att_r, att_i, rad_r, rad_i, pbuf, TG);
    }

    contract_kernel<<<F_SUB, 256, 0, stream>>>(
        fr, fi, TG, TG + 8192, (float*)d_out);
}